// Round 10
// baseline (124.393 us; speedup 1.0000x reference)
//
#include <hip/hip_runtime.h>

#define B_   4
#define NQ_  512
#define NK_  512
#define D_   512
#define H_   128

typedef __attribute__((ext_vector_type(8))) short short8;
typedef __attribute__((ext_vector_type(4))) float f32x4;

__device__ __forceinline__ float fexp2(float x) { return __builtin_amdgcn_exp2f(x); }
__device__ __forceinline__ float frcp(float x)  { return __builtin_amdgcn_rcpf(x); }
__device__ __forceinline__ unsigned short f2bf(float f) {
    unsigned int u = __builtin_bit_cast(unsigned int, f);
    u += 0x7FFFu + ((u >> 16) & 1u);          // RNE
    return (unsigned short)(u >> 16);
}

// NOTE (R6): hipLaunchCooperativeKernel silently fails under graph capture.
// NOTE (R9): block-local W@V with zero-padded MFMA A-rows + global B-frags
//            produced wrong output — unverified construction, do not reuse
//            without standalone validation. This round isolates phase A.

// ws layout (float offsets)
#define WS_EQK   0          // [4096][128] fp32: exp2(2*proj) Q rows 0..2047, K rows 2048..4095
#define WS_PP    524288     // [8][4096][128] fp32 proj partials
#define WS_WP    4718592    // [64] float4 pair table (wn0, wn1, wn0+wn1, 0)
#define WS_WBF   4718848    // ushort region: [4][512][512] bf16 softmax weights
#define WS_VT    5243136    // ushort region: [4][512][512] bf16 V^T (d-major)

// ---------------------------------------------------------------------------
// prep: blockIdx.x < 32 -> proj partials (128x128 tile, k-split 8);
//       blockIdx.x >= 32 -> V transpose -> bf16 V^T. grid (64,8), 256 thr.
// ---------------------------------------------------------------------------
__global__ __launch_bounds__(256) void prep_kernel(
    const float* __restrict__ Q, const float* __restrict__ K,
    const float* __restrict__ Wq, const float* __restrict__ Wk,
    const float* __restrict__ V,
    float* __restrict__ Pp, unsigned short* __restrict__ Vt)
{
    __shared__ float smem[2 * 32 * 132];
    const int t = threadIdx.x;

    if (blockIdx.x < 32) {
        const int xb = blockIdx.x;
        const int ks = blockIdx.y;
        const bool isQ = xb < 16;
        const float* __restrict__ X = isQ ? Q : K;
        const float* __restrict__ W = isQ ? Wq : Wk;
        const int r0 = (xb & 15) * 128;
        const int k0 = ks * 64;

        float (*At)[132] = (float(*)[132])smem;
        float (*Wl)[132] = (float(*)[132])(smem + 32 * 132);

        const int cg = t & 15;
        const int rg = t >> 4;
        float acc[8][8] = {};

        for (int kc = 0; kc < 2; ++kc) {
            if (kc) __syncthreads();
            #pragma unroll
            for (int p = 0; p < 4; ++p) {
                const int idx = p * 256 + t;
                const int row = idx & 127;
                const int kq  = (idx >> 7) * 4;
                const float4 v = *reinterpret_cast<const float4*>(
                    X + (size_t)(r0 + row) * D_ + k0 + kc * 32 + kq);
                At[kq + 0][row] = v.x; At[kq + 1][row] = v.y;
                At[kq + 2][row] = v.z; At[kq + 3][row] = v.w;
            }
            #pragma unroll
            for (int p = 0; p < 4; ++p) {
                const int idx = p * 256 + t;
                const int kr  = idx >> 5;
                const int c4  = (idx & 31) * 4;
                *reinterpret_cast<float4*>(&Wl[kr][c4]) =
                    *reinterpret_cast<const float4*>(
                        W + (size_t)(k0 + kc * 32 + kr) * H_ + c4);
            }
            __syncthreads();

            #pragma unroll 4
            for (int k = 0; k < 32; ++k) {
                const float4 a0 = *reinterpret_cast<const float4*>(&At[k][rg * 8]);
                const float4 a1 = *reinterpret_cast<const float4*>(&At[k][rg * 8 + 4]);
                const float4 b0 = *reinterpret_cast<const float4*>(&Wl[k][cg * 4]);
                const float4 b1 = *reinterpret_cast<const float4*>(&Wl[k][64 + cg * 4]);
                const float aa[8] = {a0.x, a0.y, a0.z, a0.w, a1.x, a1.y, a1.z, a1.w};
                const float bb[8] = {b0.x, b0.y, b0.z, b0.w, b1.x, b1.y, b1.z, b1.w};
                #pragma unroll
                for (int r = 0; r < 8; ++r)
                    #pragma unroll
                    for (int c = 0; c < 8; ++c)
                        acc[r][c] = fmaf(aa[r], bb[c], acc[r][c]);
            }
        }

        float* __restrict__ dst = Pp + (size_t)blockIdx.y * (4096 * 128);
        #pragma unroll
        for (int r = 0; r < 8; ++r) {
            const int grow = xb * 128 + rg * 8 + r;
            *reinterpret_cast<float4*>(dst + (size_t)grow * H_ + cg * 4) =
                make_float4(acc[r][0], acc[r][1], acc[r][2], acc[r][3]);
            *reinterpret_cast<float4*>(dst + (size_t)grow * H_ + 64 + cg * 4) =
                make_float4(acc[r][4], acc[r][5], acc[r][6], acc[r][7]);
        }
    } else {
        const int id = (blockIdx.x - 32) * 8 + blockIdx.y;
        const int kt = id & 7, dt = (id >> 3) & 7, b = id >> 6;
        float (*Vl)[69] = (float(*)[69])smem;

        #pragma unroll
        for (int p = 0; p < 4; ++p) {
            const int idx = p * 256 + t;
            const int r  = idx >> 4;
            const int c4 = (idx & 15) * 4;
            const float4 v = *reinterpret_cast<const float4*>(
                V + ((size_t)b * NK_ + kt * 64 + r) * D_ + dt * 64 + c4);
            Vl[r][c4 + 0] = v.x; Vl[r][c4 + 1] = v.y;
            Vl[r][c4 + 2] = v.z; Vl[r][c4 + 3] = v.w;
        }
        __syncthreads();

        #pragma unroll
        for (int p = 0; p < 4; ++p) {
            const int idx = p * 256 + t;
            const int d  = idx >> 4;
            const int k4 = (idx & 15) * 4;
            ushort4 o;
            o.x = f2bf(Vl[k4 + 0][d]); o.y = f2bf(Vl[k4 + 1][d]);
            o.z = f2bf(Vl[k4 + 2][d]); o.w = f2bf(Vl[k4 + 3][d]);
            *reinterpret_cast<ushort4*>(
                Vt + ((size_t)b * D_ + dt * 64 + d) * NK_ + kt * 64 + k4) = o;
        }
    }
}

// ---------------------------------------------------------------------------
// proj_add: Eqk = exp2(C2 * sum_s Pp[s]) (= e^{2*proj}); builds wp table.
// ---------------------------------------------------------------------------
__global__ __launch_bounds__(256) void proj_add_kernel(
    const float* __restrict__ Pp, const float* __restrict__ wv,
    float* __restrict__ Eqk, float* __restrict__ wp)
{
    const int i = blockIdx.x * 256 + threadIdx.x;
    const float C2 = 2.88539008177792681472f;       // 2*log2(e)
    float4 s = make_float4(0.f, 0.f, 0.f, 0.f);
    #pragma unroll
    for (int p = 0; p < 8; ++p) {
        const float4 v = reinterpret_cast<const float4*>(Pp)[(size_t)p * 131072 + i];
        s.x += v.x; s.y += v.y; s.z += v.z; s.w += v.w;
    }
    s.x = fexp2(C2 * s.x); s.y = fexp2(C2 * s.y);
    s.z = fexp2(C2 * s.z); s.w = fexp2(C2 * s.w);
    reinterpret_cast<float4*>(Eqk)[i] = s;

    if (blockIdx.x == 0 && threadIdx.x < 64) {
        const float2 w2 = reinterpret_cast<const float2*>(wv)[threadIdx.x];
        const float wn0 = -2.0f * w2.x;
        const float wn1 = -2.0f * w2.y;
        reinterpret_cast<float4*>(wp)[threadIdx.x] =
            make_float4(wn0, wn1, wn0 + wn1, 0.0f);
    }
}

// ---------------------------------------------------------------------------
// score_softmax fused, 2 rows/wave: block = 4 q-rows x all 512 k, 256 thr
// (4 waves). Wave (rp, half) -> rows row0+rp*2+{0,1}, k-half half*256.
// Each Ks LDS read feeds BOTH rows (halves score-phase LDS traffic vs R8).
// score'[q,k] = sum_h wn_h / (1 + Eq_h*Ek_h), 4-way rcp fusion, zero exp2.
// Cross-half combine via LDS; bf16 weights to global (R8-identical epilogue).
// ---------------------------------------------------------------------------
__global__ __launch_bounds__(256, 2) void score_softmax_kernel(
    const float* __restrict__ Eqk, const float* __restrict__ wp,
    const int* __restrict__ valid_lens, unsigned short* __restrict__ Wbf)
{
    const int bid  = blockIdx.x;            // 0..511
    const int row0 = bid * 4;
    const int b    = row0 >> 9;
    const int t    = threadIdx.x;
    const int w    = __builtin_amdgcn_readfirstlane(t >> 6);   // 0..3
    const int lane = t & 63;
    const int rp   = w >> 1;                // row pair 0..1
    const int half = w & 1;                 // k-half

    __shared__ __align__(16) float4 Ks[2 * 64 * 33];   // 67584 B
    __shared__ float redM[4][2], redS[4][2];

    const float4* __restrict__ Q4a =
        reinterpret_cast<const float4*>(Eqk + (size_t)(row0 + rp * 2) * H_);
    const float4* __restrict__ Q4b = Q4a + 32;
    const float4* __restrict__ wp4 = reinterpret_cast<const float4*>(wp);
    const float4* __restrict__ Kp4 =
        reinterpret_cast<const float4*>(Eqk + (size_t)(2048 + b * NK_) * H_);

    float vA[4], vB[4];

    for (int c = 0; c < 4; ++c) {
        if (c) __syncthreads();
        #pragma unroll
        for (int p = 0; p < 16; ++p) {
            const int idx = p * 256 + t;        // 0..4095
            const int hh  = idx >> 11;          // 0..1
            const int r   = (idx >> 5) & 63;    // 0..63
            const int h4  = idx & 31;
            Ks[(hh * 64 + r) * 33 + h4] =
                Kp4[(size_t)(hh * 256 + c * 64 + r) * 32 + h4];
        }
        __syncthreads();

        float sA = 0.0f, sB = 0.0f;
        #pragma unroll 4
        for (int g = 0; g < 32; ++g) {
            const float4 kv = Ks[(half * 64 + lane) * 33 + g];
            const float4 qa = Q4a[g];
            const float4 qb = Q4b[g];
            const float4 wa = wp4[2 * g];
            const float4 wb = wp4[2 * g + 1];
            {
                const float e0 = qa.x * kv.x;
                const float e1 = qa.y * kv.y;
                const float e2 = qa.z * kv.z;
                const float e3 = qa.w * kv.w;
                const float D01 = 1.0f + fmaf(e0, e1, e0 + e1);
                const float D23 = 1.0f + fmaf(e2, e3, e2 + e3);
                const float n01 = fmaf(wa.y, e0, fmaf(wa.x, e1, wa.z));
                const float n23 = fmaf(wb.y, e2, fmaf(wb.x, e3, wb.z));
                const float N   = fmaf(n23, D01, n01 * D23);
                sA = fmaf(N, frcp(D01 * D23), sA);
            }
            {
                const float e0 = qb.x * kv.x;
                const float e1 = qb.y * kv.y;
                const float e2 = qb.z * kv.z;
                const float e3 = qb.w * kv.w;
                const float D01 = 1.0f + fmaf(e0, e1, e0 + e1);
                const float D23 = 1.0f + fmaf(e2, e3, e2 + e3);
                const float n01 = fmaf(wa.y, e0, fmaf(wa.x, e1, wa.z));
                const float n23 = fmaf(wb.y, e2, fmaf(wb.x, e3, wb.z));
                const float N   = fmaf(n23, D01, n01 * D23);
                sB = fmaf(N, frcp(D01 * D23), sB);
            }
        }
        vA[c] = sA;
        vB[c] = sB;
    }

    // per-wave masked stats over this wave's 256 k, for both rows
    const int vl = valid_lens[b];
    const float L2E = 1.44269504088896340736f;
    float mA = -1e30f, mB = -1e30f;
    #pragma unroll
    for (int c = 0; c < 4; ++c) {
        const int k = half * 256 + c * 64 + lane;
        vA[c] = (k < vl) ? vA[c] : -1e30f;
        vB[c] = (k < vl) ? vB[c] : -1e30f;
        mA = fmaxf(mA, vA[c]);
        mB = fmaxf(mB, vB[c]);
    }
    #pragma unroll
    for (int off = 32; off >= 1; off >>= 1) {
        mA = fmaxf(mA, __shfl_xor(mA, off, 64));
        mB = fmaxf(mB, __shfl_xor(mB, off, 64));
    }
    float sumA = 0.0f, sumB = 0.0f;
    #pragma unroll
    for (int c = 0; c < 4; ++c) {
        sumA += fexp2((vA[c] - mA) * L2E);
        sumB += fexp2((vB[c] - mB) * L2E);
    }
    #pragma unroll
    for (int off = 32; off >= 1; off >>= 1) {
        sumA += __shfl_xor(sumA, off, 64);
        sumB += __shfl_xor(sumB, off, 64);
    }
    if (lane == 0) {
        redM[rp * 2 + 0][half] = mA; redS[rp * 2 + 0][half] = sumA;
        redM[rp * 2 + 1][half] = mB; redS[rp * 2 + 1][half] = sumB;
    }
    __syncthreads();

    const float m0A = redM[rp * 2][0],     m1A = redM[rp * 2][1];
    const float s0A = redS[rp * 2][0],     s1A = redS[rp * 2][1];
    const float m0B = redM[rp * 2 + 1][0], m1B = redM[rp * 2 + 1][1];
    const float s0B = redS[rp * 2 + 1][0], s1B = redS[rp * 2 + 1][1];
    const float MA = fmaxf(m0A, m1A);     // finite: vl >= 1
    const float MB = fmaxf(m0B, m1B);
    const float SA = fmaf(s0A, fexp2((m0A - MA) * L2E),
                          s1A * fexp2((m1A - MA) * L2E));
    const float SB = fmaf(s0B, fexp2((m0B - MB) * L2E),
                          s1B * fexp2((m1B - MB) * L2E));
    const float invA = frcp(SA);
    const float invB = frcp(SB);

    unsigned short* __restrict__ dstA =
        Wbf + (size_t)(row0 + rp * 2) * NK_ + half * 256;
    unsigned short* __restrict__ dstB = dstA + NK_;
    #pragma unroll
    for (int c = 0; c < 4; ++c) {
        dstA[c * 64 + lane] = f2bf(fexp2((vA[c] - MA) * L2E) * invA);
        dstB[c * 64 + lane] = f2bf(fexp2((vB[c] - MB) * L2E) * invB);
    }
}

// ---------------------------------------------------------------------------
// av_gemm (bf16 MFMA 16x16x32): O[b] = W@V. Block 64q x 64d, 4 waves,
// grid (8,8,4). A (weights) and Bt (=V^T) k-contiguous -> ds_read_b128.
// Verbatim from R8 (verified).
// ---------------------------------------------------------------------------
__global__ __launch_bounds__(256) void av_gemm_kernel(
    const unsigned short* __restrict__ Wbf, const unsigned short* __restrict__ Vt,
    float* __restrict__ O)
{
    const int c0 = blockIdx.x * 64;
    const int r0 = blockIdx.y * 64;
    const int b  = blockIdx.z;
    const int t  = threadIdx.x;
    const int wave = __builtin_amdgcn_readfirstlane(t >> 6);
    const int lane = t & 63;
    const int m    = lane & 15;
    const int quad = lane >> 4;

    __shared__ unsigned short Al [64][136];
    __shared__ unsigned short Btl[64][136];

    f32x4 acc0 = {0.f,0.f,0.f,0.f}, acc1 = {0.f,0.f,0.f,0.f};
    f32x4 acc2 = {0.f,0.f,0.f,0.f}, acc3 = {0.f,0.f,0.f,0.f};

    for (int kc = 0; kc < 4; ++kc) {
        if (kc) __syncthreads();
        #pragma unroll
        for (int p = 0; p < 4; ++p) {
            const int idx = p * 256 + t;
            const int rl = idx >> 4;
            const int k8 = (idx & 15) * 8;
            *reinterpret_cast<uint4*>(&Al[rl][k8]) =
                *reinterpret_cast<const uint4*>(
                    Wbf + ((size_t)b * NQ_ + r0 + rl) * NK_ + kc * 128 + k8);
            *reinterpret_cast<uint4*>(&Btl[rl][k8]) =
                *reinterpret_cast<const uint4*>(
                    Vt + ((size_t)b * D_ + c0 + rl) * NK_ + kc * 128 + k8);
        }
        __syncthreads();

        #pragma unroll
        for (int sub = 0; sub < 4; ++sub) {
            const int kcol = sub * 32 + quad * 8;
            const short8 a = *reinterpret_cast<const short8*>(&Al[wave * 16 + m][kcol]);
            const short8 b0 = *reinterpret_cast<const short8*>(&Btl[ 0 + m][kcol]);
            const short8 b1 = *reinterpret_cast<const short8*>(&Btl[16 + m][kcol]);
            const short8 b2 = *reinterpret_cast<const short8*>(&Btl[32 + m][kcol]);
            const short8 b3 = *reinterpret_cast<const short8*>(&Btl[48 + m][kcol]);
            acc0 = __builtin_amdgcn_mfma_f32_16x16x32_bf16(a, b0, acc0, 0, 0, 0);
            acc1 = __builtin_amdgcn_mfma_f32_16x16x32_bf16(a, b1, acc1, 0, 0, 0);
            acc2 = __builtin_amdgcn_mfma_f32_16x16x32_bf16(a, b2, acc2, 0, 0, 0);
            acc3 = __builtin_amdgcn_mfma_f32_16x16x32_bf16(a, b3, acc3, 0, 0, 0);
        }
    }

    const size_t rowbase = (size_t)b * NQ_ + r0 + wave * 16 + quad * 4;
    #pragma unroll
    for (int i = 0; i < 4; ++i) {
        float* __restrict__ orow = O + (rowbase + i) * D_ + c0 + m;
        orow[ 0] = acc0[i];
        orow[16] = acc1[i];
        orow[32] = acc2[i];
        orow[48] = acc3[i];
    }
}

extern "C" void kernel_launch(void* const* d_in, const int* in_sizes, int n_in,
                              void* d_out, int out_size, void* d_ws, size_t ws_size,
                              hipStream_t stream) {
    (void)in_sizes; (void)n_in; (void)out_size; (void)ws_size;

    const float* Q   = (const float*)d_in[0];
    const float* K   = (const float*)d_in[1];
    const float* V   = (const float*)d_in[2];
    const float* Wq  = (const float*)d_in[3];
    const float* Wk  = (const float*)d_in[4];
    const float* wv  = (const float*)d_in[5];
    const int*   vl  = (const int*)d_in[6];
    float* out = (float*)d_out;

    float* ws  = (float*)d_ws;
    float* Eqk = ws + WS_EQK;
    float* Pp  = ws + WS_PP;
    float* wp  = ws + WS_WP;
    unsigned short* Wbf = (unsigned short*)(ws + WS_WBF);
    unsigned short* Vt  = (unsigned short*)(ws + WS_VT);

    prep_kernel<<<dim3(64, 8), 256, 0, stream>>>(Q, K, Wq, Wk, V, Pp, Vt);
    proj_add_kernel<<<dim3(512), 256, 0, stream>>>(Pp, wv, Eqk, wp);
    score_softmax_kernel<<<dim3(512), 256, 0, stream>>>(Eqk, wp, vl, Wbf);
    av_gemm_kernel<<<dim3(8, 8, 4), 256, 0, stream>>>(Wbf, Vt, out);
}

// Round 11
// 118.901 us; speedup vs baseline: 1.0462x; 1.0462x over previous
//
#include <hip/hip_runtime.h>

#define B_   4
#define NQ_  512
#define NK_  512
#define D_   512
#define H_   128

typedef __attribute__((ext_vector_type(8))) short short8;
typedef __attribute__((ext_vector_type(4))) float f32x4;

__device__ __forceinline__ float fexp2(float x) { return __builtin_amdgcn_exp2f(x); }
__device__ __forceinline__ float frcp(float x)  { return __builtin_amdgcn_rcpf(x); }
__device__ __forceinline__ unsigned short f2bf(float f) {
    unsigned int u = __builtin_bit_cast(unsigned int, f);
    u += 0x7FFFu + ((u >> 16) & 1u);          // RNE
    return (unsigned short)(u >> 16);
}

// NOTE (R6): hipLaunchCooperativeKernel silently fails under graph capture.
// NOTE (R9): block-local W@V with zero-padded MFMA A-rows + global B-frags is
//            an unverified-broken construction — do not reuse.
// NOTE (R10): score occupancy (16 waves/CU) beats LDS-traffic halving at
//            8 waves/CU — keep the 512-thr 1-row/wave score.

// ws layout (float offsets)
#define WS_EQK   0          // [4096][128] fp32: exp2(2*proj), Q rows 0..2047, K rows 2048..4095
#define WS_WP    524288     // [64] float4 pair table (wn0, wn1, wn0+wn1, 0)
#define WS_WBF   524544     // ushort region: [4][512][512] bf16 softmax weights
#define WS_VT    1048832    // ushort region: [4][512][512] bf16 V^T (d-major)

// ---------------------------------------------------------------------------
// prep2: grid (512), 256 thr.
//   blocks 0..255: proj, 32 rows x 64 cols, FULL K=512 (no k-split) ->
//                  Eqk = exp2(C2 * X@W) written directly (kills proj_add).
//   blocks 256..511: V transpose -> bf16 V^T (R8-identical).
//   block 0 also emits the wp pair table.
// ---------------------------------------------------------------------------
__global__ __launch_bounds__(256) void prep2_kernel(
    const float* __restrict__ Q, const float* __restrict__ K,
    const float* __restrict__ Wq, const float* __restrict__ Wk,
    const float* __restrict__ V, const float* __restrict__ wv,
    float* __restrict__ Eqk, float* __restrict__ wp,
    unsigned short* __restrict__ Vt)
{
    __shared__ __align__(16) float smem[64 * 36 + 64 * 68];   // 26.6 KB
    const int t = threadIdx.x;
    const float C2 = 2.88539008177792681472f;   // 2*log2(e)

    if (blockIdx.x == 0 && t < 64) {
        const float2 w2 = reinterpret_cast<const float2*>(wv)[t];
        const float wn0 = -2.0f * w2.x;
        const float wn1 = -2.0f * w2.y;
        reinterpret_cast<float4*>(wp)[t] =
            make_float4(wn0, wn1, wn0 + wn1, 0.0f);
    }

    if (blockIdx.x < 256) {
        // ----- proj: 32 rows x 64 cols, full K -----
        const int rt = blockIdx.x >> 1;       // 0..127
        const int ct = blockIdx.x & 1;        // 0..1
        const int r0 = rt * 32;               // combined row (0..4064)
        const bool isQ = r0 < 2048;           // 32-row tile never spans Q/K
        const float* __restrict__ X = isQ ? Q : K;
        const float* __restrict__ W = isQ ? Wq : Wk;
        const int xr0 = isQ ? r0 : r0 - 2048;
        const int c0  = ct * 64;

        float (*At)[36] = (float(*)[36])smem;             // [k][row]
        float (*Wl)[68] = (float(*)[68])(smem + 64 * 36); // [k][col]

        const int cg = t & 15;    // cols 4*cg..+3
        const int rg = t >> 4;    // rows 2*rg..+1
        float acc[2][4] = {};

        for (int kc = 0; kc < 8; ++kc) {
            const int k0 = kc * 64;
            if (kc) __syncthreads();
            // stage X tile (32 rows x 64 k), transposed
            #pragma unroll
            for (int p = 0; p < 2; ++p) {
                const int idx = p * 256 + t;       // 0..511
                const int row = idx >> 4;          // 0..31
                const int kq  = (idx & 15) * 4;
                const float4 v = *reinterpret_cast<const float4*>(
                    X + (size_t)(xr0 + row) * D_ + k0 + kq);
                At[kq + 0][row] = v.x; At[kq + 1][row] = v.y;
                At[kq + 2][row] = v.z; At[kq + 3][row] = v.w;
            }
            // stage W tile (64 k x 64 cols), natural
            #pragma unroll
            for (int p = 0; p < 4; ++p) {
                const int idx = p * 256 + t;       // 0..1023
                const int kr  = idx >> 4;          // 0..63
                const int c4  = (idx & 15) * 4;
                *reinterpret_cast<float4*>(&Wl[kr][c4]) =
                    *reinterpret_cast<const float4*>(
                        W + (size_t)(k0 + kr) * H_ + c0 + c4);
            }
            __syncthreads();

            #pragma unroll 8
            for (int k = 0; k < 64; ++k) {
                const float a0 = At[k][rg * 2];
                const float a1 = At[k][rg * 2 + 1];
                const float4 b4 = *reinterpret_cast<const float4*>(&Wl[k][cg * 4]);
                const float bb[4] = {b4.x, b4.y, b4.z, b4.w};
                #pragma unroll
                for (int c = 0; c < 4; ++c) {
                    acc[0][c] = fmaf(a0, bb[c], acc[0][c]);
                    acc[1][c] = fmaf(a1, bb[c], acc[1][c]);
                }
            }
        }

        #pragma unroll
        for (int r = 0; r < 2; ++r) {
            float4 o;
            o.x = fexp2(C2 * acc[r][0]); o.y = fexp2(C2 * acc[r][1]);
            o.z = fexp2(C2 * acc[r][2]); o.w = fexp2(C2 * acc[r][3]);
            *reinterpret_cast<float4*>(
                Eqk + (size_t)(r0 + rg * 2 + r) * H_ + c0 + cg * 4) = o;
        }
    } else {
        // ----- transposeV: V (k-major fp32) -> Vt (d-major bf16) -----
        const int id = blockIdx.x - 256;          // 0..255
        const int kt = id & 7, dt = (id >> 3) & 7, b = id >> 6;
        float (*Vl)[69] = (float(*)[69])smem;     // [64][69] = 17.7 KB

        #pragma unroll
        for (int p = 0; p < 4; ++p) {
            const int idx = p * 256 + t;
            const int r  = idx >> 4;
            const int c4 = (idx & 15) * 4;
            const float4 v = *reinterpret_cast<const float4*>(
                V + ((size_t)b * NK_ + kt * 64 + r) * D_ + dt * 64 + c4);
            Vl[r][c4 + 0] = v.x; Vl[r][c4 + 1] = v.y;
            Vl[r][c4 + 2] = v.z; Vl[r][c4 + 3] = v.w;
        }
        __syncthreads();

        #pragma unroll
        for (int p = 0; p < 4; ++p) {
            const int idx = p * 256 + t;
            const int d  = idx >> 4;
            const int k4 = (idx & 15) * 4;
            ushort4 o;
            o.x = f2bf(Vl[k4 + 0][d]); o.y = f2bf(Vl[k4 + 1][d]);
            o.z = f2bf(Vl[k4 + 2][d]); o.w = f2bf(Vl[k4 + 3][d]);
            *reinterpret_cast<ushort4*>(
                Vt + ((size_t)b * D_ + dt * 64 + d) * NK_ + kt * 64 + k4) = o;
        }
    }
}

// ---------------------------------------------------------------------------
// score_softmax fused (R8 verbatim — verified): block = 4 q-rows x all 512 k,
// 512 thr (8 waves). Wave w -> row rb*4 + (w>>1), k-half (w&1)*256.
// score'[q,k] = sum_h wn_h / (1 + Eq_h*Ek_h), 4-way rcp fusion, zero exp2
// in the hot loop. Cross-wave combine via LDS; writes bf16 weights.
// ---------------------------------------------------------------------------
__global__ __launch_bounds__(512, 4) void score_softmax_kernel(
    const float* __restrict__ Eqk, const float* __restrict__ wp,
    const int* __restrict__ valid_lens, unsigned short* __restrict__ Wbf)
{
    const int rb   = blockIdx.x;            // 0..511
    const int t    = threadIdx.x;
    const int w    = __builtin_amdgcn_readfirstlane(t >> 6);   // 0..7
    const int lane = t & 63;
    const int rloc = w >> 1;                // 0..3
    const int half = w & 1;                 // k-half
    const int row  = rb * 4 + rloc;         // 0..2047
    const int b    = row >> 9;

    __shared__ __align__(16) float4 Ks[2 * 64 * 33];   // two 64-k chunks
    __shared__ float redM[4][2], redS[4][2];

    const float4* __restrict__ Q4 =
        reinterpret_cast<const float4*>(Eqk + (size_t)row * H_);
    const float4* __restrict__ wp4 = reinterpret_cast<const float4*>(wp);
    const float4* __restrict__ Kp4 =
        reinterpret_cast<const float4*>(Eqk + (size_t)(2048 + b * NK_) * H_);

    float vals[4];

    for (int c = 0; c < 4; ++c) {
        if (c) __syncthreads();
        #pragma unroll
        for (int p = 0; p < 8; ++p) {
            const int idx = p * 512 + t;        // 0..4095
            const int hh  = idx >> 11;          // 0..1
            const int r   = (idx >> 5) & 63;    // 0..63
            const int h4  = idx & 31;
            Ks[(hh * 64 + r) * 33 + h4] =
                Kp4[(size_t)(hh * 256 + c * 64 + r) * 32 + h4];
        }
        __syncthreads();

        float s = 0.0f;
        #pragma unroll 4
        for (int g = 0; g < 32; ++g) {
            const float4 kv = Ks[(half * 64 + lane) * 33 + g];
            const float4 qa = Q4[g];
            const float4 wa = wp4[2 * g];
            const float4 wb = wp4[2 * g + 1];
            const float e0 = qa.x * kv.x;
            const float e1 = qa.y * kv.y;
            const float e2 = qa.z * kv.z;
            const float e3 = qa.w * kv.w;
            const float D01 = 1.0f + fmaf(e0, e1, e0 + e1);
            const float D23 = 1.0f + fmaf(e2, e3, e2 + e3);
            const float n01 = fmaf(wa.y, e0, fmaf(wa.x, e1, wa.z));
            const float n23 = fmaf(wb.y, e2, fmaf(wb.x, e3, wb.z));
            const float N   = fmaf(n23, D01, n01 * D23);
            s = fmaf(N, frcp(D01 * D23), s);
        }
        vals[c] = s;
    }

    // per-wave masked stats over this wave's 256 k
    const int vl = valid_lens[b];
    const float L2E = 1.44269504088896340736f;
    float m = -1e30f;
    #pragma unroll
    for (int c = 0; c < 4; ++c) {
        const int k = half * 256 + c * 64 + lane;
        vals[c] = (k < vl) ? vals[c] : -1e30f;
        m = fmaxf(m, vals[c]);
    }
    #pragma unroll
    for (int off = 32; off >= 1; off >>= 1)
        m = fmaxf(m, __shfl_xor(m, off, 64));
    float sum = 0.0f;
    #pragma unroll
    for (int c = 0; c < 4; ++c)
        sum += fexp2((vals[c] - m) * L2E);
    #pragma unroll
    for (int off = 32; off >= 1; off >>= 1)
        sum += __shfl_xor(sum, off, 64);

    if (lane == 0) { redM[rloc][half] = m; redS[rloc][half] = sum; }
    __syncthreads();

    const float m0 = redM[rloc][0], m1 = redM[rloc][1];
    const float s0 = redS[rloc][0], s1 = redS[rloc][1];
    const float M  = fmaxf(m0, m1);   // finite: vl>=1 so half 0 has a valid k
    const float S  = fmaf(s0, fexp2((m0 - M) * L2E),
                          s1 * fexp2((m1 - M) * L2E));
    const float inv = frcp(S);

    unsigned short* __restrict__ dst = Wbf + (size_t)row * NK_ + half * 256;
    #pragma unroll
    for (int c = 0; c < 4; ++c)
        dst[c * 64 + lane] = f2bf(fexp2((vals[c] - M) * L2E) * inv);
}

// ---------------------------------------------------------------------------
// av_gemm (bf16 MFMA 16x16x32, R8 verbatim — verified): O[b] = W@V.
// Block 64q x 64d, 4 waves, grid (8,8,4).
// ---------------------------------------------------------------------------
__global__ __launch_bounds__(256) void av_gemm_kernel(
    const unsigned short* __restrict__ Wbf, const unsigned short* __restrict__ Vt,
    float* __restrict__ O)
{
    const int c0 = blockIdx.x * 64;
    const int r0 = blockIdx.y * 64;
    const int b  = blockIdx.z;
    const int t  = threadIdx.x;
    const int wave = __builtin_amdgcn_readfirstlane(t >> 6);
    const int lane = t & 63;
    const int m    = lane & 15;
    const int quad = lane >> 4;

    __shared__ unsigned short Al [64][136];
    __shared__ unsigned short Btl[64][136];

    f32x4 acc0 = {0.f,0.f,0.f,0.f}, acc1 = {0.f,0.f,0.f,0.f};
    f32x4 acc2 = {0.f,0.f,0.f,0.f}, acc3 = {0.f,0.f,0.f,0.f};

    for (int kc = 0; kc < 4; ++kc) {
        if (kc) __syncthreads();
        #pragma unroll
        for (int p = 0; p < 4; ++p) {
            const int idx = p * 256 + t;
            const int rl = idx >> 4;
            const int k8 = (idx & 15) * 8;
            *reinterpret_cast<uint4*>(&Al[rl][k8]) =
                *reinterpret_cast<const uint4*>(
                    Wbf + ((size_t)b * NQ_ + r0 + rl) * NK_ + kc * 128 + k8);
            *reinterpret_cast<uint4*>(&Btl[rl][k8]) =
                *reinterpret_cast<const uint4*>(
                    Vt + ((size_t)b * D_ + c0 + rl) * NK_ + kc * 128 + k8);
        }
        __syncthreads();

        #pragma unroll
        for (int sub = 0; sub < 4; ++sub) {
            const int kcol = sub * 32 + quad * 8;
            const short8 a = *reinterpret_cast<const short8*>(&Al[wave * 16 + m][kcol]);
            const short8 b0 = *reinterpret_cast<const short8*>(&Btl[ 0 + m][kcol]);
            const short8 b1 = *reinterpret_cast<const short8*>(&Btl[16 + m][kcol]);
            const short8 b2 = *reinterpret_cast<const short8*>(&Btl[32 + m][kcol]);
            const short8 b3 = *reinterpret_cast<const short8*>(&Btl[48 + m][kcol]);
            acc0 = __builtin_amdgcn_mfma_f32_16x16x32_bf16(a, b0, acc0, 0, 0, 0);
            acc1 = __builtin_amdgcn_mfma_f32_16x16x32_bf16(a, b1, acc1, 0, 0, 0);
            acc2 = __builtin_amdgcn_mfma_f32_16x16x32_bf16(a, b2, acc2, 0, 0, 0);
            acc3 = __builtin_amdgcn_mfma_f32_16x16x32_bf16(a, b3, acc3, 0, 0, 0);
        }
    }

    const size_t rowbase = (size_t)b * NQ_ + r0 + wave * 16 + quad * 4;
    #pragma unroll
    for (int i = 0; i < 4; ++i) {
        float* __restrict__ orow = O + (rowbase + i) * D_ + c0 + m;
        orow[ 0] = acc0[i];
        orow[16] = acc1[i];
        orow[32] = acc2[i];
        orow[48] = acc3[i];
    }
}

extern "C" void kernel_launch(void* const* d_in, const int* in_sizes, int n_in,
                              void* d_out, int out_size, void* d_ws, size_t ws_size,
                              hipStream_t stream) {
    (void)in_sizes; (void)n_in; (void)out_size; (void)ws_size;

    const float* Q   = (const float*)d_in[0];
    const float* K   = (const float*)d_in[1];
    const float* V   = (const float*)d_in[2];
    const float* Wq  = (const float*)d_in[3];
    const float* Wk  = (const float*)d_in[4];
    const float* wv  = (const float*)d_in[5];
    const int*   vl  = (const int*)d_in[6];
    float* out = (float*)d_out;

    float* ws  = (float*)d_ws;
    float* Eqk = ws + WS_EQK;
    float* wp  = ws + WS_WP;
    unsigned short* Wbf = (unsigned short*)(ws + WS_WBF);
    unsigned short* Vt  = (unsigned short*)(ws + WS_VT);

    prep2_kernel<<<dim3(512), 256, 0, stream>>>(Q, K, Wq, Wk, V, wv, Eqk, wp, Vt);
    score_softmax_kernel<<<dim3(512), 512, 0, stream>>>(Eqk, wp, vl, Wbf);
    av_gemm_kernel<<<dim3(8, 8, 4), 256, 0, stream>>>(Wbf, Vt, out);
}